// Round 3
// baseline (500.992 us; speedup 1.0000x reference)
//
#include <hip/hip_runtime.h>
#include <math.h>

#define NMODES 32
#define NPAIR 496
#define TAYLOR_N 12
// Re-plane size: 200 * 2048 * 32. Im plane (if present) starts here.
#define PLANE 13107200LL

// T2 matrix in module-scope device memory (d_ws may be zero-sized).
// Written by setup_kernel on every kernel_launch call.
__device__ float2 g_T2[NMODES * NMODES];

__device__ __forceinline__ float2 cmul(float2 a, float2 b) {
    return make_float2(a.x * b.x - a.y * b.y, a.x * b.y + a.y * b.x);
}

// ---------------------------------------------------------------------------
// Setup kernel: one block of 1024 threads builds T2 (32x32 complex).
//   H from params  ->  U = expm(iH) (scale & square + Taylor-Horner)
//   W = U^T U      ->  mix = (1.1 I - W)^{-1} W  (Gauss-Jordan, partial pivot)
//   T2[i][j] = -kappa_i * kappa_j * (0.5*delta_ij + mix[i][j])
// ---------------------------------------------------------------------------
__global__ __launch_bounds__(1024) void setup_kernel(const float* __restrict__ params,
                                                     const float* __restrict__ kappa) {
    __shared__ float2 X[NMODES][NMODES];
    __shared__ float2 R[NMODES][NMODES];
    __shared__ float2 W[NMODES][NMODES];
    __shared__ float2 Aug[NMODES][2 * NMODES];
    __shared__ int sh_s;
    __shared__ float sh_scale;
    __shared__ int sh_piv;
    __shared__ float2 sh_pivrec;

    const int tid = threadIdx.x;
    const int i = tid >> 5;
    const int j = tid & 31;

    // --- build H ---
    float2 h;
    if (i == j) {
        float d;
        if (i < 31) {
            d = params[2 * NPAIR + i];
        } else {
            d = 0.0f;
            for (int r = 0; r < 31; ++r) d -= params[2 * NPAIR + r];
        }
        h = make_float2(d, 0.0f);
    } else {
        int a = (i < j) ? i : j;
        int b = (i < j) ? j : i;
        int idx = 31 * a - (a * (a - 1)) / 2 + (b - a - 1);  // row-major triu
        float re = params[idx];
        float im = params[NPAIR + idx];
        h = (i < j) ? make_float2(re, im) : make_float2(re, -im);
    }
    X[i][j] = h;
    __syncthreads();

    // --- inf-norm and scaling exponent ---
    if (tid == 0) {
        float nrm = 0.0f;
        for (int r = 0; r < NMODES; ++r) {
            float s = 0.0f;
            for (int c = 0; c < NMODES; ++c) {
                float2 v = X[r][c];
                s += sqrtf(v.x * v.x + v.y * v.y);
            }
            nrm = fmaxf(nrm, s);
        }
        int s = 0;
        float sc = 1.0f;
        while (nrm > 0.25f && s < 40) { nrm *= 0.5f; sc *= 0.5f; ++s; }
        sh_s = s;
        sh_scale = sc;
    }
    __syncthreads();

    // --- X = (i*H) * 2^{-s} ---
    {
        float sc = sh_scale;
        float2 v = X[i][j];
        X[i][j] = make_float2(-v.y * sc, v.x * sc);
    }
    __syncthreads();

    // --- Taylor via Horner: R = I; for k=N..1: R = I + (X*R)/k ---
    R[i][j] = make_float2((i == j) ? 1.0f : 0.0f, 0.0f);
    __syncthreads();
    for (int k = TAYLOR_N; k >= 1; --k) {
        float2 acc = make_float2(0.0f, 0.0f);
        for (int kk = 0; kk < NMODES; ++kk) {
            float2 a = X[i][kk];
            float2 b = R[kk][j];
            acc.x = fmaf(a.x, b.x, fmaf(-a.y, b.y, acc.x));
            acc.y = fmaf(a.x, b.y, fmaf(a.y, b.x, acc.y));
        }
        __syncthreads();
        float invk = 1.0f / (float)k;
        R[i][j] = make_float2(((i == j) ? 1.0f : 0.0f) + acc.x * invk, acc.y * invk);
        __syncthreads();
    }

    // --- squarings ---
    {
        int s = sh_s;
        for (int q = 0; q < s; ++q) {
            float2 acc = make_float2(0.0f, 0.0f);
            for (int kk = 0; kk < NMODES; ++kk) {
                float2 a = R[i][kk];
                float2 b = R[kk][j];
                acc.x = fmaf(a.x, b.x, fmaf(-a.y, b.y, acc.x));
                acc.y = fmaf(a.x, b.y, fmaf(a.y, b.x, acc.y));
            }
            __syncthreads();
            R[i][j] = acc;
            __syncthreads();
        }
    }

    // --- W = U^T U (no conjugation) ---
    {
        float2 acc = make_float2(0.0f, 0.0f);
        for (int kk = 0; kk < NMODES; ++kk) {
            float2 a = R[kk][i];
            float2 b = R[kk][j];
            acc.x = fmaf(a.x, b.x, fmaf(-a.y, b.y, acc.x));
            acc.y = fmaf(a.x, b.y, fmaf(a.y, b.x, acc.y));
        }
        W[i][j] = acc;
    }
    __syncthreads();

    // --- augmented [1.1 I - W | W] ---
    {
        float2 w = W[i][j];
        Aug[i][j] = make_float2(((i == j) ? 1.1f : 0.0f) - w.x, -w.y);
        Aug[i][j + NMODES] = w;
    }
    __syncthreads();

    // --- Gauss-Jordan with partial pivoting; right half -> mix ---
    for (int p = 0; p < NMODES; ++p) {
        if (tid == 0) {
            int best = p;
            float bm = -1.0f;
            for (int r = p; r < NMODES; ++r) {
                float2 v = Aug[r][p];
                float mag = v.x * v.x + v.y * v.y;
                if (mag > bm) { bm = mag; best = r; }
            }
            sh_piv = best;
        }
        __syncthreads();
        int piv = sh_piv;
        if (piv != p && i == p) {
            float2 a0 = Aug[p][j], b0 = Aug[piv][j];
            float2 a1 = Aug[p][j + NMODES], b1 = Aug[piv][j + NMODES];
            Aug[p][j] = b0; Aug[piv][j] = a0;
            Aug[p][j + NMODES] = b1; Aug[piv][j + NMODES] = a1;
        }
        __syncthreads();
        if (tid == 0) {
            float2 d = Aug[p][p];
            float den = d.x * d.x + d.y * d.y;
            sh_pivrec = make_float2(d.x / den, -d.y / den);
        }
        __syncthreads();
        if (i == p) {
            float2 pr = sh_pivrec;
            Aug[p][j] = cmul(Aug[p][j], pr);
            Aug[p][j + NMODES] = cmul(Aug[p][j + NMODES], pr);
        }
        __syncthreads();
        float2 f = Aug[i][p];
        __syncthreads();
        if (i != p) {
            float2 rp0 = Aug[p][j];
            float2 rp1 = Aug[p][j + NMODES];
            float2 v0 = Aug[i][j];
            float2 v1 = Aug[i][j + NMODES];
            v0.x -= f.x * rp0.x - f.y * rp0.y;
            v0.y -= f.x * rp0.y + f.y * rp0.x;
            v1.x -= f.x * rp1.x - f.y * rp1.y;
            v1.y -= f.x * rp1.y + f.y * rp1.x;
            Aug[i][j] = v0;
            Aug[i][j + NMODES] = v1;
        }
        __syncthreads();
    }

    // --- T2 ---
    {
        float2 mix = Aug[i][j + NMODES];
        float kk2 = fabsf(kappa[i]) * fabsf(kappa[j]);
        float re = -kk2 * (((i == j) ? 0.5f : 0.0f) + mix.x);
        float im = -kk2 * mix.y;
        g_T2[i * NMODES + j] = make_float2(re, im);
    }
}

// ---------------------------------------------------------------------------
// Main ODE kernel: 1 thread per (batch, mode). Block = 64 = 1 wave = 2 batch.
// Output layout: PLANAR. Re at [t*2048*32 + b*32 + m]; Im at PLANE + same,
// guarded by out_size (covers both planar-float32 and real-only-float32
// harness conventions).
// ---------------------------------------------------------------------------
__device__ __forceinline__ float2 f_eval(const float2* __restrict__ bufhalf,
                                         float2 ym,
                                         const float2* __restrict__ t2,
                                         float om, float nl2) {
    const float4* p = reinterpret_cast<const float4*>(bufhalf);
    float2 acc0 = make_float2(0.0f, 0.0f);
    float2 acc1 = make_float2(0.0f, 0.0f);
#pragma unroll
    for (int kk = 0; kk < 16; ++kk) {
        float4 v = p[kk];
        float2 ta = t2[2 * kk];
        float2 tb = t2[2 * kk + 1];
        acc0.x = fmaf(ta.x, v.x, acc0.x);
        acc0.x = fmaf(-ta.y, v.y, acc0.x);
        acc0.y = fmaf(ta.x, v.y, acc0.y);
        acc0.y = fmaf(ta.y, v.x, acc0.y);
        acc1.x = fmaf(tb.x, v.z, acc1.x);
        acc1.x = fmaf(-tb.y, v.w, acc1.x);
        acc1.y = fmaf(tb.x, v.w, acc1.y);
        acc1.y = fmaf(tb.y, v.z, acc1.y);
    }
    float w = fmaf(nl2, fmaf(ym.x, ym.x, ym.y * ym.y), om);
    float2 r;
    r.x = (acc0.x + acc1.x) - w * ym.y;
    r.y = (acc0.y + acc1.y) + w * ym.x;
    return r;
}

__global__ __launch_bounds__(64) void ode_kernel(const float* __restrict__ A0r,
                                                 const float* __restrict__ A0i,
                                                 const float* __restrict__ omega,
                                                 const float* __restrict__ nln,
                                                 float* __restrict__ out,
                                                 long long out_size) {
    const int lane = threadIdx.x;
    const int half = lane >> 5;
    const int m = lane & 31;
    const int b = blockIdx.x * 2 + half;

    float2 t2[NMODES];
#pragma unroll
    for (int k = 0; k < NMODES; ++k) t2[k] = g_T2[m * NMODES + k];

    const float om = omega[m];
    const float nl = nln[0];
    const float nl2 = nl * nl;
    const float dt = 1.0f / 199.0f;
    const float hdt = 0.5f * dt;
    const float sdt = dt / 6.0f;

    float2 a;
    if (m < 24) a = make_float2(A0r[b * 24 + m], A0i[b * 24 + m]);
    else        a = make_float2(1.0f, 0.0f);

    __shared__ __align__(16) float2 buf0[2][NMODES];
    __shared__ __align__(16) float2 buf1[2][NMODES];

    // t = 0 output (planar, guarded)
    {
        long long o = (long long)b * 32 + m;
        if (o < out_size) out[o] = a.x;
        if (PLANE + o < out_size) out[PLANE + o] = a.y;
    }
    buf0[half][m] = a;
    __syncthreads();

    for (int t = 1; t < 200; ++t) {
        float2 k1 = f_eval(buf0[half], a, t2, om, nl2);
        float2 y2 = make_float2(fmaf(hdt, k1.x, a.x), fmaf(hdt, k1.y, a.y));
        buf1[half][m] = y2;
        __syncthreads();

        float2 k2 = f_eval(buf1[half], y2, t2, om, nl2);
        float2 y3 = make_float2(fmaf(hdt, k2.x, a.x), fmaf(hdt, k2.y, a.y));
        buf0[half][m] = y3;
        __syncthreads();

        float2 k3 = f_eval(buf0[half], y3, t2, om, nl2);
        float2 y4 = make_float2(fmaf(dt, k3.x, a.x), fmaf(dt, k3.y, a.y));
        buf1[half][m] = y4;
        __syncthreads();

        float2 k4 = f_eval(buf1[half], y4, t2, om, nl2);

        a.x = fmaf(sdt, k1.x + 2.0f * k2.x + 2.0f * k3.x + k4.x, a.x);
        a.y = fmaf(sdt, k1.y + 2.0f * k2.y + 2.0f * k3.y + k4.y, a.y);

        buf0[half][m] = a;
        __syncthreads();

        long long o = (long long)t * 65536 + (long long)b * 32 + m;
        if (o < out_size) out[o] = a.x;
        if (PLANE + o < out_size) out[PLANE + o] = a.y;
    }
}

extern "C" void kernel_launch(void* const* d_in, const int* in_sizes, int n_in,
                              void* d_out, int out_size, void* d_ws, size_t ws_size,
                              hipStream_t stream) {
    const float* A0r = (const float*)d_in[0];
    const float* A0i = (const float*)d_in[1];
    const float* omega = (const float*)d_in[2];
    const float* kappa = (const float*)d_in[3];
    const float* nln = (const float*)d_in[4];
    const float* params = (const float*)d_in[5];

    setup_kernel<<<1, 1024, 0, stream>>>(params, kappa);
    ode_kernel<<<1024, 64, 0, stream>>>(A0r, A0i, omega, nln,
                                        (float*)d_out, (long long)out_size);
}

// Round 4
// 362.954 us; speedup vs baseline: 1.3803x; 1.3803x over previous
//
#include <hip/hip_runtime.h>
#include <math.h>

#define NMODES 32
#define NPAIR 496
#define TAYLOR_N 12

// T2 matrix in module-scope device memory (d_ws may be zero-sized).
__device__ float2 g_T2[NMODES * NMODES];

__device__ __forceinline__ float2 cmul(float2 a, float2 b) {
    return make_float2(a.x * b.x - a.y * b.y, a.x * b.y + a.y * b.x);
}

// ---------------------------------------------------------------------------
// Setup kernel: one block of 1024 threads builds T2 (32x32 complex).
//   H from params  ->  U = expm(iH) (scale & square + Taylor-Horner)
//   W = U^T U      ->  mix = (1.1 I - W)^{-1} W  (Gauss-Jordan, partial pivot)
//   T2[i][j] = -kappa_i * kappa_j * (0.5*delta_ij + mix[i][j])
// ---------------------------------------------------------------------------
__global__ __launch_bounds__(1024) void setup_kernel(const float* __restrict__ params,
                                                     const float* __restrict__ kappa) {
    __shared__ float2 X[NMODES][NMODES];
    __shared__ float2 R[NMODES][NMODES];
    __shared__ float2 W[NMODES][NMODES];
    __shared__ float2 Aug[NMODES][2 * NMODES];
    __shared__ int sh_s;
    __shared__ float sh_scale;
    __shared__ int sh_piv;
    __shared__ float2 sh_pivrec;

    const int tid = threadIdx.x;
    const int i = tid >> 5;
    const int j = tid & 31;

    // --- build H ---
    float2 h;
    if (i == j) {
        float d;
        if (i < 31) {
            d = params[2 * NPAIR + i];
        } else {
            d = 0.0f;
            for (int r = 0; r < 31; ++r) d -= params[2 * NPAIR + r];
        }
        h = make_float2(d, 0.0f);
    } else {
        int a = (i < j) ? i : j;
        int b = (i < j) ? j : i;
        int idx = 31 * a - (a * (a - 1)) / 2 + (b - a - 1);  // row-major triu
        float re = params[idx];
        float im = params[NPAIR + idx];
        h = (i < j) ? make_float2(re, im) : make_float2(re, -im);
    }
    X[i][j] = h;
    __syncthreads();

    // --- inf-norm (wave 0, parallel rows + shuffle max-reduce) ---
    if (tid < 32) {
        float s = 0.0f;
        for (int c = 0; c < NMODES; ++c) {
            float2 v = X[tid][c];
            s += sqrtf(v.x * v.x + v.y * v.y);
        }
        for (int off = 16; off > 0; off >>= 1)
            s = fmaxf(s, __shfl_down(s, off));
        if (tid == 0) {
            int sc_n = 0;
            float sc = 1.0f;
            while (s > 0.25f && sc_n < 40) { s *= 0.5f; sc *= 0.5f; ++sc_n; }
            sh_s = sc_n;
            sh_scale = sc;
        }
    }
    __syncthreads();

    // --- X = (i*H) * 2^{-s} ---
    {
        float sc = sh_scale;
        float2 v = X[i][j];
        X[i][j] = make_float2(-v.y * sc, v.x * sc);
    }
    __syncthreads();

    // --- Taylor via Horner: R = I; for k=N..1: R = I + (X*R)/k ---
    R[i][j] = make_float2((i == j) ? 1.0f : 0.0f, 0.0f);
    __syncthreads();
    for (int k = TAYLOR_N; k >= 1; --k) {
        float2 acc = make_float2(0.0f, 0.0f);
        for (int kk = 0; kk < NMODES; ++kk) {
            float2 a = X[i][kk];
            float2 b = R[kk][j];
            acc.x = fmaf(a.x, b.x, fmaf(-a.y, b.y, acc.x));
            acc.y = fmaf(a.x, b.y, fmaf(a.y, b.x, acc.y));
        }
        __syncthreads();
        float invk = 1.0f / (float)k;
        R[i][j] = make_float2(((i == j) ? 1.0f : 0.0f) + acc.x * invk, acc.y * invk);
        __syncthreads();
    }

    // --- squarings ---
    {
        int s = sh_s;
        for (int q = 0; q < s; ++q) {
            float2 acc = make_float2(0.0f, 0.0f);
            for (int kk = 0; kk < NMODES; ++kk) {
                float2 a = R[i][kk];
                float2 b = R[kk][j];
                acc.x = fmaf(a.x, b.x, fmaf(-a.y, b.y, acc.x));
                acc.y = fmaf(a.x, b.y, fmaf(a.y, b.x, acc.y));
            }
            __syncthreads();
            R[i][j] = acc;
            __syncthreads();
        }
    }

    // --- W = U^T U (no conjugation) ---
    {
        float2 acc = make_float2(0.0f, 0.0f);
        for (int kk = 0; kk < NMODES; ++kk) {
            float2 a = R[kk][i];
            float2 b = R[kk][j];
            acc.x = fmaf(a.x, b.x, fmaf(-a.y, b.y, acc.x));
            acc.y = fmaf(a.x, b.y, fmaf(a.y, b.x, acc.y));
        }
        W[i][j] = acc;
    }
    __syncthreads();

    // --- augmented [1.1 I - W | W] ---
    {
        float2 w = W[i][j];
        Aug[i][j] = make_float2(((i == j) ? 1.1f : 0.0f) - w.x, -w.y);
        Aug[i][j + NMODES] = w;
    }
    __syncthreads();

    // --- Gauss-Jordan with partial pivoting; right half -> mix ---
    for (int p = 0; p < NMODES; ++p) {
        if (tid < 32) {  // parallel argmax pivot search (wave 0)
            float2 v = Aug[tid][p];
            float mag = (tid >= p) ? (v.x * v.x + v.y * v.y) : -1.0f;
            int idx = tid;
            for (int off = 16; off > 0; off >>= 1) {
                float omg = __shfl_down(mag, off);
                int oi = __shfl_down(idx, off);
                if (omg > mag) { mag = omg; idx = oi; }
            }
            if (tid == 0) sh_piv = idx;
        }
        __syncthreads();
        int piv = sh_piv;
        if (piv != p && i == p) {
            float2 a0 = Aug[p][j], b0 = Aug[piv][j];
            float2 a1 = Aug[p][j + NMODES], b1 = Aug[piv][j + NMODES];
            Aug[p][j] = b0; Aug[piv][j] = a0;
            Aug[p][j + NMODES] = b1; Aug[piv][j + NMODES] = a1;
        }
        __syncthreads();
        if (tid == 0) {
            float2 d = Aug[p][p];
            float den = d.x * d.x + d.y * d.y;
            sh_pivrec = make_float2(d.x / den, -d.y / den);
        }
        __syncthreads();
        if (i == p) {
            float2 pr = sh_pivrec;
            Aug[p][j] = cmul(Aug[p][j], pr);
            Aug[p][j + NMODES] = cmul(Aug[p][j + NMODES], pr);
        }
        __syncthreads();
        float2 f = Aug[i][p];
        __syncthreads();
        if (i != p) {
            float2 rp0 = Aug[p][j];
            float2 rp1 = Aug[p][j + NMODES];
            float2 v0 = Aug[i][j];
            float2 v1 = Aug[i][j + NMODES];
            v0.x -= f.x * rp0.x - f.y * rp0.y;
            v0.y -= f.x * rp0.y + f.y * rp0.x;
            v1.x -= f.x * rp1.x - f.y * rp1.y;
            v1.y -= f.x * rp1.y + f.y * rp1.x;
            Aug[i][j] = v0;
            Aug[i][j + NMODES] = v1;
        }
        __syncthreads();
    }

    // --- T2 ---
    {
        float2 mix = Aug[i][j + NMODES];
        float kk2 = fabsf(kappa[i]) * fabsf(kappa[j]);
        float re = -kk2 * (((i == j) ? 0.5f : 0.0f) + mix.x);
        float im = -kk2 * mix.y;
        g_T2[i * NMODES + j] = make_float2(re, im);
    }
}

// ---------------------------------------------------------------------------
// Main ODE kernel, split-K x2: block = 64 threads = 1 wave = 1 batch.
// lane = (m = lane>>1, h = lane&1). Each lane holds half of T2 row m
// (k = h*16 .. h*16+15) and computes a half dot; halves combine via
// __shfl_xor(.,1). 2048 waves -> 2 waves/SIMD (vs 1 before) to hide
// LDS round-trip + barrier vmcnt-drain latency.
//
// LDS layout (padded): slot(k) = k + (k>=16 ? 2 : 0)  => h=1 half starts at
// byte 144 (16B-aligned, banks disjoint from h=0 half at every unroll step).
// Output: real part only (out_size == 200*2048*32 confirmed by WRITE_SIZE).
// ---------------------------------------------------------------------------
__device__ __forceinline__ float2 f_eval(const float4* __restrict__ xq,
                                         float2 ym,
                                         const float2* __restrict__ t2h,
                                         float om, float nl2) {
    float2 acc0 = make_float2(0.0f, 0.0f);
    float2 acc1 = make_float2(0.0f, 0.0f);
#pragma unroll
    for (int j = 0; j < 8; ++j) {
        float4 v = xq[j];  // complex x[h*16+2j], x[h*16+2j+1]
        float2 ta = t2h[2 * j];
        float2 tb = t2h[2 * j + 1];
        acc0.x = fmaf(ta.x, v.x, acc0.x);
        acc0.x = fmaf(-ta.y, v.y, acc0.x);
        acc0.y = fmaf(ta.x, v.y, acc0.y);
        acc0.y = fmaf(ta.y, v.x, acc0.y);
        acc1.x = fmaf(tb.x, v.z, acc1.x);
        acc1.x = fmaf(-tb.y, v.w, acc1.x);
        acc1.y = fmaf(tb.x, v.w, acc1.y);
        acc1.y = fmaf(tb.y, v.z, acc1.y);
    }
    float2 acc = make_float2(acc0.x + acc1.x, acc0.y + acc1.y);
    acc.x += __shfl_xor(acc.x, 1);  // combine K-halves; both lanes get full sum
    acc.y += __shfl_xor(acc.y, 1);
    float w = fmaf(nl2, fmaf(ym.x, ym.x, ym.y * ym.y), om);
    return make_float2(acc.x - w * ym.y, acc.y + w * ym.x);
}

__global__ __launch_bounds__(64) void ode_kernel(const float* __restrict__ A0r,
                                                 const float* __restrict__ A0i,
                                                 const float* __restrict__ omega,
                                                 const float* __restrict__ nln,
                                                 float* __restrict__ out,
                                                 long long out_size) {
    const int lane = threadIdx.x;
    const int m = lane >> 1;
    const int h = lane & 1;
    const int b = blockIdx.x;

    // half T2 row: 16 complex = 32 VGPRs
    float2 t2h[16];
#pragma unroll
    for (int j = 0; j < 16; ++j) t2h[j] = g_T2[m * NMODES + h * 16 + j];

    const float om = omega[m];
    const float nl = nln[0];
    const float nl2 = nl * nl;
    const float dt = 1.0f / 199.0f;
    const float hdt = 0.5f * dt;
    const float sdt = dt / 6.0f;

    float2 a;
    if (m < 24) a = make_float2(A0r[b * 24 + m], A0i[b * 24 + m]);
    else        a = make_float2(1.0f, 0.0f);

    __shared__ __align__(16) float2 xbuf[36];  // 32 complex + 2-slot pad at 16
    const int swi = m + ((m >= 16) ? 2 : 0);   // write slot for mode m
    const float4* xq = reinterpret_cast<const float4*>(xbuf) + 9 * h;  // h=1 -> byte 144

    // t = 0 output (real plane only, guarded)
    if (h == 0) {
        long long o = (long long)b * 32 + m;
        if (o < out_size) out[o] = a.x;
        xbuf[swi] = a;
    }
    __syncthreads();

    for (int t = 1; t < 200; ++t) {
        float2 k1 = f_eval(xq, a, t2h, om, nl2);
        float2 y2 = make_float2(fmaf(hdt, k1.x, a.x), fmaf(hdt, k1.y, a.y));
        if (h == 0) xbuf[swi] = y2;
        __syncthreads();

        float2 k2 = f_eval(xq, y2, t2h, om, nl2);
        float2 y3 = make_float2(fmaf(hdt, k2.x, a.x), fmaf(hdt, k2.y, a.y));
        if (h == 0) xbuf[swi] = y3;
        __syncthreads();

        float2 k3 = f_eval(xq, y3, t2h, om, nl2);
        float2 y4 = make_float2(fmaf(dt, k3.x, a.x), fmaf(dt, k3.y, a.y));
        if (h == 0) xbuf[swi] = y4;
        __syncthreads();

        float2 k4 = f_eval(xq, y4, t2h, om, nl2);

        a.x = fmaf(sdt, k1.x + 2.0f * k2.x + 2.0f * k3.x + k4.x, a.x);
        a.y = fmaf(sdt, k1.y + 2.0f * k2.y + 2.0f * k3.y + k4.y, a.y);

        if (h == 0) {
            xbuf[swi] = a;
            long long o = (long long)t * 65536 + (long long)b * 32 + m;
            if (o < out_size) out[o] = a.x;
        }
        __syncthreads();
    }
}

extern "C" void kernel_launch(void* const* d_in, const int* in_sizes, int n_in,
                              void* d_out, int out_size, void* d_ws, size_t ws_size,
                              hipStream_t stream) {
    const float* A0r = (const float*)d_in[0];
    const float* A0i = (const float*)d_in[1];
    const float* omega = (const float*)d_in[2];
    const float* kappa = (const float*)d_in[3];
    const float* nln = (const float*)d_in[4];
    const float* params = (const float*)d_in[5];

    setup_kernel<<<1, 1024, 0, stream>>>(params, kappa);
    ode_kernel<<<2048, 64, 0, stream>>>(A0r, A0i, omega, nln,
                                        (float*)d_out, (long long)out_size);
}